// Round 1
// baseline (1694.656 us; speedup 1.0000x reference)
//
#include <hip/hip_runtime.h>
#include <math.h>
#include <stdint.h>

#define B_ 4
#define T_ 2048
#define C_ 2048
#define NH 16
#define NKV 4
#define HD 128
#define NREP 4
#define KVC (NKV*HD)   // 512

typedef __attribute__((ext_vector_type(8))) __bf16 bf16x8;
typedef __attribute__((ext_vector_type(4))) float floatx4;

__device__ __forceinline__ float b2f(unsigned short u) {
  union { unsigned int i; float f; } v; v.i = ((unsigned int)u) << 16; return v.f;
}
__device__ __forceinline__ unsigned short f2b(float f) {
  union { float f; unsigned int i; } v; v.f = f;
  unsigned int r = v.i + 0x7fffu + ((v.i >> 16) & 1u);
  return (unsigned short)(r >> 16);
}

// ---------------- fp32 -> bf16 convert ----------------
__global__ void cvt_bf16_kernel(const float* __restrict__ X,
                                unsigned short* __restrict__ Y, int n) {
  int i = (blockIdx.x * 256 + threadIdx.x) * 4;
  if (i >= n) return;
  float4 v = *(const float4*)(X + i);
  ushort4 o;
  o.x = f2b(v.x); o.y = f2b(v.y); o.z = f2b(v.z); o.w = f2b(v.w);
  *(ushort4*)(Y + i) = o;
}

// ---------------- W (KxN fp32) -> Wt (NxK bf16) ----------------
__global__ void transpose_cvt_kernel(const float* __restrict__ W,
                                     unsigned short* __restrict__ Wt,
                                     int K, int N) {
  __shared__ float tile[32][33];
  int n = blockIdx.x * 32 + threadIdx.x;
  int kbase = blockIdx.y * 32;
  #pragma unroll
  for (int i = 0; i < 32; i += 8)
    tile[threadIdx.y + i][threadIdx.x] = W[(size_t)(kbase + threadIdx.y + i) * N + n];
  __syncthreads();
  int k = kbase + threadIdx.x;
  int nb = blockIdx.x * 32;
  #pragma unroll
  for (int i = 0; i < 32; i += 8)
    Wt[(size_t)(nb + threadIdx.y + i) * K + k] = f2b(tile[threadIdx.x][threadIdx.y + i]);
}

// ---------------- bf16 MFMA GEMM, B^T input (m92/m93 structure) ----------------
// C[m,n] = sum_k A[m,k] * Bt[n,k].  128x128 tile, BK=32, 4 waves (2x2 of 64x64).
#define BM 128
#define BN 128
#define BK 32
#define LDK 40   // padded LDS row stride (bf16 elems): 80B rows -> 2-way bank alias (free)

template<int STORE_BF16>
__global__ __launch_bounds__(256) void gemm_bt(
    const unsigned short* __restrict__ A,   // M x K bf16
    const unsigned short* __restrict__ Bt,  // N x K bf16
    void* __restrict__ Cout,                // M x N (bf16 or f32)
    int M, int N, int K)
{
  __shared__ unsigned short As[BM * LDK];
  __shared__ unsigned short Bs[BN * LDK];
  int tid = threadIdx.x;
  int m0 = blockIdx.x * BM;
  int n0 = blockIdx.y * BN;
  int wave = tid >> 6, lane = tid & 63;
  int wm = (wave & 1) * 64, wn = (wave >> 1) * 64;
  int fr = lane & 15;          // fragment row (m or n within 16-tile)
  int kg = lane >> 4;          // k-group: k = kg*8 + j

  floatx4 acc[4][4];
  #pragma unroll
  for (int i = 0; i < 4; i++)
    #pragma unroll
    for (int j = 0; j < 4; j++)
      acc[i][j] = (floatx4){0.f, 0.f, 0.f, 0.f};

  int srow = tid >> 2;            // 0..63
  int scol = (tid & 3) * 8;       // 0,8,16,24

  for (int k0 = 0; k0 < K; k0 += BK) {
    uint4 a0 = *(const uint4*)(A  + (size_t)(m0 + srow) * K + k0 + scol);
    uint4 a1 = *(const uint4*)(A  + (size_t)(m0 + 64 + srow) * K + k0 + scol);
    uint4 b0 = *(const uint4*)(Bt + (size_t)(n0 + srow) * K + k0 + scol);
    uint4 b1 = *(const uint4*)(Bt + (size_t)(n0 + 64 + srow) * K + k0 + scol);
    __syncthreads();   // prior iter's fragment reads done
    *(uint4*)&As[srow * LDK + scol]        = a0;
    *(uint4*)&As[(64 + srow) * LDK + scol] = a1;
    *(uint4*)&Bs[srow * LDK + scol]        = b0;
    *(uint4*)&Bs[(64 + srow) * LDK + scol] = b1;
    __syncthreads();

    bf16x8 af[4], bfr[4];
    #pragma unroll
    for (int i = 0; i < 4; i++) {
      union { uint4 u; bf16x8 v; } t;
      t.u = *(const uint4*)&As[(wm + i * 16 + fr) * LDK + kg * 8];
      af[i] = t.v;
    }
    #pragma unroll
    for (int j = 0; j < 4; j++) {
      union { uint4 u; bf16x8 v; } t;
      t.u = *(const uint4*)&Bs[(wn + j * 16 + fr) * LDK + kg * 8];
      bfr[j] = t.v;
    }
    #pragma unroll
    for (int i = 0; i < 4; i++)
      #pragma unroll
      for (int j = 0; j < 4; j++)
        acc[i][j] = __builtin_amdgcn_mfma_f32_16x16x32_bf16(af[i], bfr[j], acc[i][j], 0, 0, 0);
  }

  // C/D layout: col = lane&15, row = (lane>>4)*4 + reg   [measured m89/m91]
  int erow = (lane >> 4) * 4;
  int ecol = lane & 15;
  #pragma unroll
  for (int i = 0; i < 4; i++)
    #pragma unroll
    for (int j = 0; j < 4; j++) {
      int gm = m0 + wm + i * 16 + erow;
      int gn = n0 + wn + j * 16 + ecol;
      #pragma unroll
      for (int r = 0; r < 4; r++) {
        float v = acc[i][j][r];
        if (STORE_BF16)
          ((unsigned short*)Cout)[(size_t)(gm + r) * N + gn] = f2b(v);
        else
          ((float*)Cout)[(size_t)(gm + r) * N + gn] = v;
      }
    }
}

// ---------------- RoPE (in-place on bf16, pairs (2i,2i+1)) ----------------
__global__ void rope_kernel(unsigned short* __restrict__ X,
                            const float* __restrict__ FC, int nheads) {
  long long idx = (long long)blockIdx.x * 256 + threadIdx.x;
  int p = (int)(idx & (HD / 2 - 1));
  long long t1 = idx >> 6;           // / (HD/2)
  int h = (int)(t1 % nheads);
  long long row = t1 / nheads;       // b*T + t
  int t = (int)(row & (T_ - 1));
  float c = FC[((size_t)t * (HD / 2) + p) * 2 + 0];
  float s = FC[((size_t)t * (HD / 2) + p) * 2 + 1];
  unsigned short* ptr = X + row * (size_t)(nheads * HD) + h * HD + 2 * p;
  float a = b2f(ptr[0]), b = b2f(ptr[1]);
  ptr[0] = f2b(a * c - b * s);
  ptr[1] = f2b(a * s + b * c);
}

// ---------------- flash attention (fp32 VALU, online softmax) ----------------
#define BR 64
#define BC 64
#define QLD (HD + 8)   // padded LDS stride for Q/K/V tiles (bf16 elems)
#define SP 68          // padded stride for S tile (floats)

__global__ __launch_bounds__(256) void attn_kernel(
    const unsigned short* __restrict__ Q,   // (B*T) x 2048
    const unsigned short* __restrict__ Kg,  // (B*T) x 512
    const unsigned short* __restrict__ Vg,  // (B*T) x 512
    unsigned short* __restrict__ O)         // (B*T) x 2048
{
  __shared__ unsigned short Qs[BR * QLD];
  __shared__ unsigned short KVs[BC * QLD];
  __shared__ float Ss[BR * SP];
  __shared__ float mrow[BR], lrow[BR], arow[BR];

  int bh = blockIdx.x;
  int qt = blockIdx.y;
  int b = bh >> 4, h = bh & 15, g = h >> 2;
  int tid = threadIdx.x;

  size_t qbase = ((size_t)(b * T_ + qt * BR)) * C_ + h * HD;
  #pragma unroll
  for (int i = 0; i < 4; i++) {
    int cc = tid + 256 * i;
    int r = cc >> 4, d = (cc & 15) * 8;
    *(uint4*)&Qs[r * QLD + d] = *(const uint4*)(Q + qbase + (size_t)r * C_ + d);
  }
  if (tid < BR) { mrow[tid] = -INFINITY; lrow[tid] = 0.f; }

  int rt  = (tid >> 4) * 4;
  int ct4 = (tid & 15) * 4;
  int co8 = (tid & 15) * 8;
  float o[4][8];
  #pragma unroll
  for (int i = 0; i < 4; i++)
    #pragma unroll
    for (int j = 0; j < 8; j++) o[i][j] = 0.f;

  const float scale = 0.08838834764831845f;
  size_t kvrow0 = (size_t)(b * T_) * KVC + g * HD;

  for (int s0 = 0; s0 <= qt * BR; s0 += BC) {
    __syncthreads();            // prior O-update done with KVs/Ss; Q tile visible
    #pragma unroll
    for (int i = 0; i < 4; i++) {           // stage K tile
      int cc = tid + 256 * i;
      int r = cc >> 4, d = (cc & 15) * 8;
      *(uint4*)&KVs[r * QLD + d] = *(const uint4*)(Kg + kvrow0 + (size_t)(s0 + r) * KVC + d);
    }
    __syncthreads();

    // S = Q K^T : 4x4 register block per thread
    float sc[4][4];
    #pragma unroll
    for (int i = 0; i < 4; i++)
      #pragma unroll
      for (int j = 0; j < 4; j++) sc[i][j] = 0.f;
    for (int dc = 0; dc < HD; dc += 8) {
      uint4 qv[4], kv[4];
      #pragma unroll
      for (int i = 0; i < 4; i++) qv[i] = *(const uint4*)&Qs[(rt + i) * QLD + dc];
      #pragma unroll
      for (int j = 0; j < 4; j++) kv[j] = *(const uint4*)&KVs[(ct4 + j) * QLD + dc];
      #pragma unroll
      for (int w = 0; w < 4; w++) {
        float ql[4], qh[4], kl[4], kh[4];
        #pragma unroll
        for (int i = 0; i < 4; i++) {
          unsigned int u = ((const unsigned int*)&qv[i])[w];
          union { unsigned int i; float f; } aa, bb;
          aa.i = u << 16; bb.i = u & 0xffff0000u;
          ql[i] = aa.f; qh[i] = bb.f;
        }
        #pragma unroll
        for (int j = 0; j < 4; j++) {
          unsigned int u = ((const unsigned int*)&kv[j])[w];
          union { unsigned int i; float f; } aa, bb;
          aa.i = u << 16; bb.i = u & 0xffff0000u;
          kl[j] = aa.f; kh[j] = bb.f;
        }
        #pragma unroll
        for (int i = 0; i < 4; i++)
          #pragma unroll
          for (int j = 0; j < 4; j++)
            sc[i][j] += ql[i] * kl[j] + qh[i] * kh[j];
      }
    }
    int q0 = qt * BR + rt;
    #pragma unroll
    for (int i = 0; i < 4; i++)
      #pragma unroll
      for (int j = 0; j < 4; j++) {
        int gs = s0 + ct4 + j;
        Ss[(rt + i) * SP + ct4 + j] = (gs <= q0 + i) ? sc[i][j] * scale : -INFINITY;
      }
    __syncthreads();

    // online softmax: 4 threads per row, 16 cols each
    {
      int r = tid >> 2, cs = (tid & 3) * 16;
      float vals[16]; float mx = -INFINITY;
      #pragma unroll
      for (int c = 0; c < 16; c++) { vals[c] = Ss[r * SP + cs + c]; mx = fmaxf(mx, vals[c]); }
      mx = fmaxf(mx, __shfl_xor(mx, 1));
      mx = fmaxf(mx, __shfl_xor(mx, 2));
      float mold = mrow[r];
      float mnew = fmaxf(mold, mx);
      float sum = 0.f;
      #pragma unroll
      for (int c = 0; c < 16; c++) {
        float p = __expf(vals[c] - mnew);
        Ss[r * SP + cs + c] = p;
        sum += p;
      }
      sum += __shfl_xor(sum, 1);
      sum += __shfl_xor(sum, 2);
      if ((tid & 3) == 0) {
        float al = __expf(mold - mnew);
        arow[r] = al; mrow[r] = mnew; lrow[r] = al * lrow[r] + sum;
      }
    }
    // stage V tile into the same buffer (K no longer needed)
    #pragma unroll
    for (int i = 0; i < 4; i++) {
      int cc = tid + 256 * i;
      int r = cc >> 4, d = (cc & 15) * 8;
      *(uint4*)&KVs[r * QLD + d] = *(const uint4*)(Vg + kvrow0 + (size_t)(s0 + r) * KVC + d);
    }
    __syncthreads();

    // O = alpha*O + P V : 4 rows x 8 cols per thread
    #pragma unroll
    for (int i = 0; i < 4; i++) {
      float al = arow[rt + i];
      #pragma unroll
      for (int j = 0; j < 8; j++) o[i][j] *= al;
    }
    for (int s = 0; s < BC; s++) {
      float p0 = Ss[(rt + 0) * SP + s];
      float p1 = Ss[(rt + 1) * SP + s];
      float p2 = Ss[(rt + 2) * SP + s];
      float p3 = Ss[(rt + 3) * SP + s];
      uint4 vv = *(const uint4*)&KVs[s * QLD + co8];
      float vf[8];
      #pragma unroll
      for (int w = 0; w < 4; w++) {
        unsigned int u = ((const unsigned int*)&vv)[w];
        union { unsigned int i; float f; } aa, bb;
        aa.i = u << 16; bb.i = u & 0xffff0000u;
        vf[2 * w] = aa.f; vf[2 * w + 1] = bb.f;
      }
      #pragma unroll
      for (int j = 0; j < 8; j++) {
        o[0][j] += p0 * vf[j]; o[1][j] += p1 * vf[j];
        o[2][j] += p2 * vf[j]; o[3][j] += p3 * vf[j];
      }
    }
  }

  #pragma unroll
  for (int i = 0; i < 4; i++) {
    float inv = 1.f / lrow[rt + i];
    unsigned int pk[4];
    #pragma unroll
    for (int w = 0; w < 4; w++) {
      unsigned short lo = f2b(o[i][2 * w] * inv);
      unsigned short hi = f2b(o[i][2 * w + 1] * inv);
      pk[w] = (unsigned int)lo | ((unsigned int)hi << 16);
    }
    size_t orow = ((size_t)(b * T_ + qt * BR + rt + i)) * C_ + h * HD + co8;
    *(uint4*)(O + orow) = *(uint4*)pk;
  }
}

// ---------------- launcher ----------------
extern "C" void kernel_launch(void* const* d_in, const int* in_sizes, int n_in,
                              void* d_out, int out_size, void* d_ws, size_t ws_size,
                              hipStream_t stream) {
  (void)in_sizes; (void)n_in; (void)out_size; (void)ws_size;
  const float* x  = (const float*)d_in[0];
  const float* fc = (const float*)d_in[1];
  const float* wq = (const float*)d_in[2];
  const float* wk = (const float*)d_in[3];
  const float* wv = (const float*)d_in[4];
  const float* wo = (const float*)d_in[5];
  float* out = (float*)d_out;

  char* ws = (char*)d_ws;
  unsigned short* xb  = (unsigned short*)(ws);                 // 32 MB  (B*T x C bf16)
  unsigned short* qb  = (unsigned short*)(ws + 33554432);      // 32 MB
  unsigned short* kb  = (unsigned short*)(ws + 67108864);      // 8 MB
  unsigned short* vb  = (unsigned short*)(ws + 75497472);      // 8 MB
  unsigned short* wqT = (unsigned short*)(ws + 83886080);      // 8 MB
  unsigned short* wkT = (unsigned short*)(ws + 92274688);      // 2 MB
  unsigned short* wvT = (unsigned short*)(ws + 94371840);      // 2 MB
  unsigned short* woT = (unsigned short*)(ws + 96468992);      // 8 MB  (total 100 MB)
  unsigned short* yb  = xb;  // reuse: x no longer needed after QKV GEMMs

  int nx = B_ * T_ * C_;
  cvt_bf16_kernel<<<nx / 4 / 256, 256, 0, stream>>>(x, xb, nx);
  transpose_cvt_kernel<<<dim3(C_ / 32, C_ / 32), dim3(32, 8), 0, stream>>>(wq, wqT, C_, C_);
  transpose_cvt_kernel<<<dim3(KVC / 32, C_ / 32), dim3(32, 8), 0, stream>>>(wk, wkT, C_, KVC);
  transpose_cvt_kernel<<<dim3(KVC / 32, C_ / 32), dim3(32, 8), 0, stream>>>(wv, wvT, C_, KVC);
  transpose_cvt_kernel<<<dim3(C_ / 32, C_ / 32), dim3(32, 8), 0, stream>>>(wo, woT, C_, C_);

  int M = B_ * T_;
  gemm_bt<1><<<dim3(M / BM, C_ / BN), 256, 0, stream>>>(xb, wqT, qb, M, C_, C_);
  gemm_bt<1><<<dim3(M / BM, KVC / BN), 256, 0, stream>>>(xb, wkT, kb, M, KVC, C_);
  gemm_bt<1><<<dim3(M / BM, KVC / BN), 256, 0, stream>>>(xb, wvT, vb, M, KVC, C_);

  long long qp = (long long)B_ * T_ * NH * (HD / 2);
  rope_kernel<<<(unsigned)(qp / 256), 256, 0, stream>>>(qb, fc, NH);
  long long kp = (long long)B_ * T_ * NKV * (HD / 2);
  rope_kernel<<<(unsigned)(kp / 256), 256, 0, stream>>>(kb, fc, NKV);

  attn_kernel<<<dim3(B_ * NH, T_ / BR), 256, 0, stream>>>(qb, kb, vb, yb);

  gemm_bt<0><<<dim3(M / BM, C_ / BN), 256, 0, stream>>>(yb, woT, out, M, C_, C_);
}

// Round 2
// 702.347 us; speedup vs baseline: 2.4128x; 2.4128x over previous
//
#include <hip/hip_runtime.h>
#include <math.h>
#include <stdint.h>

#define B_ 4
#define T_ 2048
#define C_ 2048
#define NH 16
#define NKV 4
#define HD 128
#define NREP 4
#define KVC (NKV*HD)   // 512

typedef __attribute__((ext_vector_type(8))) __bf16 bf16x8;
typedef __attribute__((ext_vector_type(4))) float floatx4;

__device__ __forceinline__ float b2f(unsigned short u) {
  union { unsigned int i; float f; } v; v.i = ((unsigned int)u) << 16; return v.f;
}
__device__ __forceinline__ unsigned short f2b(float f) {
  union { float f; unsigned int i; } v; v.f = f;
  unsigned int r = v.i + 0x7fffu + ((v.i >> 16) & 1u);
  return (unsigned short)(r >> 16);
}

// ---------------- fp32 -> bf16 convert ----------------
__global__ void cvt_bf16_kernel(const float* __restrict__ X,
                                unsigned short* __restrict__ Y, int n) {
  int i = (blockIdx.x * 256 + threadIdx.x) * 4;
  if (i >= n) return;
  float4 v = *(const float4*)(X + i);
  ushort4 o;
  o.x = f2b(v.x); o.y = f2b(v.y); o.z = f2b(v.z); o.w = f2b(v.w);
  *(ushort4*)(Y + i) = o;
}

// ---------------- W (KxN fp32) -> Wt (NxK bf16) ----------------
__global__ void transpose_cvt_kernel(const float* __restrict__ W,
                                     unsigned short* __restrict__ Wt,
                                     int K, int N) {
  __shared__ float tile[32][33];
  int n = blockIdx.x * 32 + threadIdx.x;
  int kbase = blockIdx.y * 32;
  #pragma unroll
  for (int i = 0; i < 32; i += 8)
    tile[threadIdx.y + i][threadIdx.x] = W[(size_t)(kbase + threadIdx.y + i) * N + n];
  __syncthreads();
  int k = kbase + threadIdx.x;
  int nb = blockIdx.x * 32;
  #pragma unroll
  for (int i = 0; i < 32; i += 8)
    Wt[(size_t)(nb + threadIdx.y + i) * K + k] = f2b(tile[threadIdx.x][threadIdx.y + i]);
}

// ---------------- V (B*T x 512 bf16) -> Vt (B,NKV,HD,T bf16) ----------------
__global__ void transpose_v_kernel(const unsigned short* __restrict__ V,
                                   unsigned short* __restrict__ Vt) {
  __shared__ unsigned short tile[32][33];
  int d0 = blockIdx.x * 32;
  int sg = blockIdx.y * 32;          // global row in (B*T)
  int b = sg >> 11;                  // / T_
  int s0 = sg & (T_ - 1);
  #pragma unroll
  for (int i = 0; i < 32; i += 8)
    tile[threadIdx.y + i][threadIdx.x] =
        V[(size_t)(sg + threadIdx.y + i) * KVC + d0 + threadIdx.x];
  __syncthreads();
  #pragma unroll
  for (int i = 0; i < 32; i += 8) {
    int d = d0 + threadIdx.y + i;
    int g = d >> 7, dl = d & 127;
    Vt[((size_t)(b * NKV + g) * HD + dl) * T_ + s0 + threadIdx.x] =
        tile[threadIdx.x][threadIdx.y + i];
  }
}

// ---------------- bf16 MFMA GEMM, B^T input (m92/m93 structure) ----------------
#define BM 128
#define BN 128
#define BK 32
#define LDK 40

template<int STORE_BF16>
__global__ __launch_bounds__(256) void gemm_bt(
    const unsigned short* __restrict__ A,   // M x K bf16
    const unsigned short* __restrict__ Bt,  // N x K bf16
    void* __restrict__ Cout,                // M x N (bf16 or f32)
    int M, int N, int K)
{
  __shared__ unsigned short As[BM * LDK];
  __shared__ unsigned short Bs[BN * LDK];
  int tid = threadIdx.x;
  int m0 = blockIdx.x * BM;
  int n0 = blockIdx.y * BN;
  int wave = tid >> 6, lane = tid & 63;
  int wm = (wave & 1) * 64, wn = (wave >> 1) * 64;
  int fr = lane & 15;
  int kg = lane >> 4;

  floatx4 acc[4][4];
  #pragma unroll
  for (int i = 0; i < 4; i++)
    #pragma unroll
    for (int j = 0; j < 4; j++)
      acc[i][j] = (floatx4){0.f, 0.f, 0.f, 0.f};

  int srow = tid >> 2;
  int scol = (tid & 3) * 8;

  for (int k0 = 0; k0 < K; k0 += BK) {
    uint4 a0 = *(const uint4*)(A  + (size_t)(m0 + srow) * K + k0 + scol);
    uint4 a1 = *(const uint4*)(A  + (size_t)(m0 + 64 + srow) * K + k0 + scol);
    uint4 b0 = *(const uint4*)(Bt + (size_t)(n0 + srow) * K + k0 + scol);
    uint4 b1 = *(const uint4*)(Bt + (size_t)(n0 + 64 + srow) * K + k0 + scol);
    __syncthreads();
    *(uint4*)&As[srow * LDK + scol]        = a0;
    *(uint4*)&As[(64 + srow) * LDK + scol] = a1;
    *(uint4*)&Bs[srow * LDK + scol]        = b0;
    *(uint4*)&Bs[(64 + srow) * LDK + scol] = b1;
    __syncthreads();

    bf16x8 af[4], bfr[4];
    #pragma unroll
    for (int i = 0; i < 4; i++) {
      union { uint4 u; bf16x8 v; } t;
      t.u = *(const uint4*)&As[(wm + i * 16 + fr) * LDK + kg * 8];
      af[i] = t.v;
    }
    #pragma unroll
    for (int j = 0; j < 4; j++) {
      union { uint4 u; bf16x8 v; } t;
      t.u = *(const uint4*)&Bs[(wn + j * 16 + fr) * LDK + kg * 8];
      bfr[j] = t.v;
    }
    #pragma unroll
    for (int i = 0; i < 4; i++)
      #pragma unroll
      for (int j = 0; j < 4; j++)
        acc[i][j] = __builtin_amdgcn_mfma_f32_16x16x32_bf16(af[i], bfr[j], acc[i][j], 0, 0, 0);
  }

  int erow = (lane >> 4) * 4;
  int ecol = lane & 15;
  #pragma unroll
  for (int i = 0; i < 4; i++)
    #pragma unroll
    for (int j = 0; j < 4; j++) {
      int gm = m0 + wm + i * 16 + erow;
      int gn = n0 + wn + j * 16 + ecol;
      #pragma unroll
      for (int r = 0; r < 4; r++) {
        float v = acc[i][j][r];
        if (STORE_BF16)
          ((unsigned short*)Cout)[(size_t)(gm + r) * N + gn] = f2b(v);
        else
          ((float*)Cout)[(size_t)(gm + r) * N + gn] = v;
      }
    }
}

// ---------------- RoPE (in-place on bf16, pairs (2i,2i+1)) ----------------
__global__ void rope_kernel(unsigned short* __restrict__ X,
                            const float* __restrict__ FC, int nheads) {
  long long idx = (long long)blockIdx.x * 256 + threadIdx.x;
  int p = (int)(idx & (HD / 2 - 1));
  long long t1 = idx >> 6;
  int h = (int)(t1 % nheads);
  long long row = t1 / nheads;
  int t = (int)(row & (T_ - 1));
  float c = FC[((size_t)t * (HD / 2) + p) * 2 + 0];
  float s = FC[((size_t)t * (HD / 2) + p) * 2 + 1];
  unsigned short* ptr = X + row * (size_t)(nheads * HD) + h * HD + 2 * p;
  float a = b2f(ptr[0]), b = b2f(ptr[1]);
  ptr[0] = f2b(a * c - b * s);
  ptr[1] = f2b(a * s + b * c);
}

// ---------------- flash attention, MFMA (bf16), online softmax in-register --
#define ABR 64     // q rows per block
#define ABC 64     // kv cols per iter
#define KLD 136    // Ks LDS stride (elems), 272 B rows, 16B aligned
#define VLD 72     // Vs LDS stride (s-cols 64 + 8), 144 B rows
#define PLD 72     // Ps LDS stride

__global__ __launch_bounds__(256) void attn_mfma_kernel(
    const unsigned short* __restrict__ Q,   // (B*T) x 2048, roped
    const unsigned short* __restrict__ Kg,  // (B*T) x 512,  roped
    const unsigned short* __restrict__ Vt,  // (B*NKV) x HD x T
    unsigned short* __restrict__ O)         // (B*T) x 2048
{
  __shared__ unsigned short Ks[ABC * KLD];   // 17408 B
  __shared__ unsigned short Vs[HD * VLD];    // 18432 B
  __shared__ unsigned short Ps[ABR * PLD];   //  9216 B  (wave-private 16-row strips)

  int bh = blockIdx.x;
  int qt = blockIdx.y;
  int b = bh >> 4, h = bh & 15, g = h >> 2;
  int tid = threadIdx.x;
  int wave = tid >> 6, lane = tid & 63;
  int fr = lane & 15, kg = lane >> 4;
  int erow = kg * 4;

  // Q A-fragments in registers: rows (qt*64 + wave*16 + fr), k = kk*32 + kg*8 + j
  bf16x8 qf[4];
  {
    const unsigned short* qrow =
        Q + ((size_t)(b * T_ + qt * ABR + wave * 16 + fr)) * C_ + h * HD;
    #pragma unroll
    for (int kk = 0; kk < 4; kk++) {
      union { uint4 u; bf16x8 v; } t;
      t.u = *(const uint4*)(qrow + kk * 32 + kg * 8);
      qf[kk] = t.v;
    }
  }

  floatx4 oacc[8];
  #pragma unroll
  for (int d = 0; d < 8; d++) oacc[d] = (floatx4){0.f, 0.f, 0.f, 0.f};
  float m_[4], l_[4];
  #pragma unroll
  for (int r = 0; r < 4; r++) { m_[r] = -INFINITY; l_[r] = 0.f; }

  const float scale = 0.08838834764831845f;
  size_t kbase = (size_t)(b * T_) * KVC + g * HD;
  size_t vbase = ((size_t)(b * NKV + g) * HD) * T_;
  int q_global = qt * ABR + wave * 16 + erow;   // + r for the actual row

  for (int s0 = 0; s0 <= qt * ABR; s0 += ABC) {
    __syncthreads();   // all waves done reading prior Ks/Vs
    {  // stage K tile: 64 rows x 128 cols
      int r = tid >> 2, c0 = (tid & 3) * 8;
      const unsigned short* src = Kg + kbase + (size_t)(s0 + r) * KVC;
      #pragma unroll
      for (int it = 0; it < 4; it++)
        *(uint4*)&Ks[r * KLD + c0 + it * 32] = *(const uint4*)(src + c0 + it * 32);
    }
    {  // stage Vt tile: 128 d-rows x 64 s-cols
      int r = tid >> 1, c0 = (tid & 1) * 8;
      const unsigned short* src = Vt + vbase + (size_t)r * T_ + s0;
      #pragma unroll
      for (int it = 0; it < 4; it++)
        *(uint4*)&Vs[r * VLD + c0 + it * 16] = *(const uint4*)(src + c0 + it * 16);
    }
    __syncthreads();

    // S = Q K^T : 4 s-tiles of 16, K in B-layout from row-major Ks
    floatx4 sc[4];
    #pragma unroll
    for (int t = 0; t < 4; t++) sc[t] = (floatx4){0.f, 0.f, 0.f, 0.f};
    #pragma unroll
    for (int kk = 0; kk < 4; kk++) {
      #pragma unroll
      for (int t = 0; t < 4; t++) {
        union { uint4 u; bf16x8 v; } kf;
        kf.u = *(const uint4*)&Ks[(t * 16 + fr) * KLD + kk * 32 + kg * 8];
        sc[t] = __builtin_amdgcn_mfma_f32_16x16x32_bf16(qf[kk], kf.v, sc[t], 0, 0, 0);
      }
    }

    // scale + causal mask + row max (C layout: row = erow + r, col = lane&15)
    float mx[4];
    #pragma unroll
    for (int r = 0; r < 4; r++) mx[r] = -INFINITY;
    #pragma unroll
    for (int t = 0; t < 4; t++) {
      int s_g = s0 + t * 16 + fr;
      #pragma unroll
      for (int r = 0; r < 4; r++) {
        float v = sc[t][r] * scale;
        v = (s_g <= q_global + r) ? v : -INFINITY;
        sc[t][r] = v;
        mx[r] = fmaxf(mx[r], v);
      }
    }
    #pragma unroll
    for (int r = 0; r < 4; r++) {
      mx[r] = fmaxf(mx[r], __shfl_xor(mx[r], 1));
      mx[r] = fmaxf(mx[r], __shfl_xor(mx[r], 2));
      mx[r] = fmaxf(mx[r], __shfl_xor(mx[r], 4));
      mx[r] = fmaxf(mx[r], __shfl_xor(mx[r], 8));
    }
    float alpha[4], rsum[4];
    #pragma unroll
    for (int r = 0; r < 4; r++) {
      float mnew = fmaxf(m_[r], mx[r]);
      alpha[r] = __expf(m_[r] - mnew);
      m_[r] = mnew;
      rsum[r] = 0.f;
    }
    #pragma unroll
    for (int t = 0; t < 4; t++)
      #pragma unroll
      for (int r = 0; r < 4; r++) {
        float p = __expf(sc[t][r] - m_[r]);
        sc[t][r] = p;
        rsum[r] += p;
      }
    #pragma unroll
    for (int r = 0; r < 4; r++) {
      rsum[r] += __shfl_xor(rsum[r], 1);
      rsum[r] += __shfl_xor(rsum[r], 2);
      rsum[r] += __shfl_xor(rsum[r], 4);
      rsum[r] += __shfl_xor(rsum[r], 8);
      l_[r] = alpha[r] * l_[r] + rsum[r];
    }
    #pragma unroll
    for (int d = 0; d < 8; d++)
      #pragma unroll
      for (int r = 0; r < 4; r++)
        oacc[d][r] *= alpha[r];

    // P (C layout) -> LDS strip (wave-private, no barrier)
    #pragma unroll
    for (int t = 0; t < 4; t++)
      #pragma unroll
      for (int r = 0; r < 4; r++)
        Ps[(wave * 16 + erow + r) * PLD + t * 16 + fr] = f2b(sc[t][r]);

    // PV: A-frags from Ps, B-frags from Vs (row-major d)
    bf16x8 pf[2];
    #pragma unroll
    for (int kk = 0; kk < 2; kk++) {
      union { uint4 u; bf16x8 v; } t;
      t.u = *(const uint4*)&Ps[(wave * 16 + fr) * PLD + kk * 32 + kg * 8];
      pf[kk] = t.v;
    }
    #pragma unroll
    for (int d = 0; d < 8; d++) {
      #pragma unroll
      for (int kk = 0; kk < 2; kk++) {
        union { uint4 u; bf16x8 v; } vf;
        vf.u = *(const uint4*)&Vs[(d * 16 + fr) * VLD + kk * 32 + kg * 8];
        oacc[d] = __builtin_amdgcn_mfma_f32_16x16x32_bf16(pf[kk], vf.v, oacc[d], 0, 0, 0);
      }
    }
  }

  // epilogue: normalize and store (rows erow+r, cols d*16 + fr)
  #pragma unroll
  for (int r = 0; r < 4; r++) {
    float inv = 1.f / l_[r];
    size_t orow = ((size_t)(b * T_ + qt * ABR + wave * 16 + erow + r)) * C_ + h * HD;
    #pragma unroll
    for (int d = 0; d < 8; d++)
      O[orow + d * 16 + fr] = f2b(oacc[d][r] * inv);
  }
}

// ---------------- launcher ----------------
extern "C" void kernel_launch(void* const* d_in, const int* in_sizes, int n_in,
                              void* d_out, int out_size, void* d_ws, size_t ws_size,
                              hipStream_t stream) {
  (void)in_sizes; (void)n_in; (void)out_size; (void)ws_size;
  const float* x  = (const float*)d_in[0];
  const float* fc = (const float*)d_in[1];
  const float* wq = (const float*)d_in[2];
  const float* wk = (const float*)d_in[3];
  const float* wv = (const float*)d_in[4];
  const float* wo = (const float*)d_in[5];
  float* out = (float*)d_out;

  char* ws = (char*)d_ws;
  unsigned short* xb  = (unsigned short*)(ws);                 // 32 MB
  unsigned short* qb  = (unsigned short*)(ws + 33554432);      // 32 MB
  unsigned short* kb  = (unsigned short*)(ws + 67108864);      // 8 MB
  unsigned short* vb  = (unsigned short*)(ws + 75497472);      // 8 MB
  unsigned short* wqT = (unsigned short*)(ws + 83886080);      // 8 MB
  unsigned short* wkT = (unsigned short*)(ws + 92274688);      // 2 MB
  unsigned short* wvT = (unsigned short*)(ws + 94371840);      // 2 MB
  unsigned short* woT = (unsigned short*)(ws + 96468992);      // 8 MB (total 100 MiB)
  unsigned short* vt  = wqT;  // reuse: wqT dead after Q GEMM
  unsigned short* yb  = xb;   // reuse: x dead after QKV GEMMs

  int nx = B_ * T_ * C_;
  cvt_bf16_kernel<<<nx / 4 / 256, 256, 0, stream>>>(x, xb, nx);
  transpose_cvt_kernel<<<dim3(C_ / 32, C_ / 32), dim3(32, 8), 0, stream>>>(wq, wqT, C_, C_);
  transpose_cvt_kernel<<<dim3(KVC / 32, C_ / 32), dim3(32, 8), 0, stream>>>(wk, wkT, C_, KVC);
  transpose_cvt_kernel<<<dim3(KVC / 32, C_ / 32), dim3(32, 8), 0, stream>>>(wv, wvT, C_, KVC);
  transpose_cvt_kernel<<<dim3(C_ / 32, C_ / 32), dim3(32, 8), 0, stream>>>(wo, woT, C_, C_);

  int M = B_ * T_;
  gemm_bt<1><<<dim3(M / BM, C_ / BN), 256, 0, stream>>>(xb, wqT, qb, M, C_, C_);
  gemm_bt<1><<<dim3(M / BM, KVC / BN), 256, 0, stream>>>(xb, wkT, kb, M, KVC, C_);
  gemm_bt<1><<<dim3(M / BM, KVC / BN), 256, 0, stream>>>(xb, wvT, vb, M, KVC, C_);

  // V -> Vt (d-major), overlays wqT which is dead now
  transpose_v_kernel<<<dim3(KVC / 32, B_ * T_ / 32), dim3(32, 8), 0, stream>>>(vb, vt);

  long long qp = (long long)B_ * T_ * NH * (HD / 2);
  rope_kernel<<<(unsigned)(qp / 256), 256, 0, stream>>>(qb, fc, NH);
  long long kp = (long long)B_ * T_ * NKV * (HD / 2);
  rope_kernel<<<(unsigned)(kp / 256), 256, 0, stream>>>(kb, fc, NKV);

  attn_mfma_kernel<<<dim3(B_ * NH, T_ / ABR), 256, 0, stream>>>(qb, kb, vt, yb);

  gemm_bt<0><<<dim3(M / BM, C_ / BN), 256, 0, stream>>>(yb, woT, out, M, C_, C_);
}